// Round 12
// baseline (491.641 us; speedup 1.0000x reference)
//
#include <hip/hip_runtime.h>
#include <hip/hip_bf16.h>

// ChildSumTreeLSTM, fp32 in/out, depth=17, N=2^18-1, D_IN=H=128.
// R7: rcp-based sigm/tanh.
// R17 (470 us, verified): k_pairleaf2 (512 thr, wave-per-col-tile) + k_pair
//      A=14 + k_lvl 13..0.
// R18: (a) pairleaf2 LDS 69632 -> 52224 by aliasing the SC epilogue scratch
//      onto XA (safe: leaf64_wave never uses SC; node32_wave gets one uniform
//      __syncthreads() between its MMA loop (last XA reads) and the SCw
//      epilogue writes) => 3 blocks/CU (was 2).
//      (b) k_pairint2 = wave-per-col-tile internal pair for A=14 ONLY
//      (full validity everywhere: Pa=16384). Mid phases read children c from
//      global fp32 (the single R17-unverified path -> bisect step for the
//      R16 bug). k_lvl keeps 13..0.
// Weights: W plain bf16, U split-2 hi/lo bf16 (pre-swizzled to B-frag order).
// h global bf16, c global fp32. Shifted rows: row = node+1.

typedef __bf16 bf16_t;
typedef __bf16 bf16x8 __attribute__((ext_vector_type(8)));
typedef float  f32x4  __attribute__((ext_vector_type(4)));

#define MFMA16(a, b, c) __builtin_amdgcn_mfma_f32_16x16x32_bf16((a), (b), (c), 0, 0, 0)

__device__ __forceinline__ float rcp_(float x) { return __builtin_amdgcn_rcpf(x); }
// bf16-rounded outputs: 1-ulp v_rcp_f32 error is invisible.
__device__ __forceinline__ float sigm(float x) { return rcp_(1.0f + __expf(-x)); }
__device__ __forceinline__ float tanh_(float x) {
    float a = fabsf(x);
    float e = __expf(2.0f * a);
    float t = fmaf(-2.0f, rcp_(e + 1.0f), 1.0f);
    return copysignf(t, x);
}

__device__ __forceinline__ void cvt16(const float* __restrict__ src, bf16_t* __restrict__ dst)
{
    float tmp[16];
    *(float4*)&tmp[0]  = ((const float4*)src)[0];
    *(float4*)&tmp[4]  = ((const float4*)src)[1];
    *(float4*)&tmp[8]  = ((const float4*)src)[2];
    *(float4*)&tmp[12] = ((const float4*)src)[3];
    bf16_t b[16];
#pragma unroll
    for (int j = 0; j < 16; j++) b[j] = (bf16_t)tmp[j];
    *(bf16x8*)&dst[0] = *(bf16x8*)&b[0];
    *(bf16x8*)&dst[8] = *(bf16x8*)&b[8];
}

__device__ __forceinline__ void zero16(bf16_t* __restrict__ dst)
{
    bf16x8 z = (bf16x8)(bf16_t)0.f;
    *(bf16x8*)&dst[0] = z;
    *(bf16x8*)&dst[8] = z;
}

// SW layout (bf16 elems): W g (0=Wi 1=Wf 2=Wo 3=Wu) at g*16384, plain.
// U u (0=Ui 1=Uf 2=Uo 3=Uu) at 65536 + u*32768 (hi), +16384 (lo).
// idx = ((nt*4+kb)*64 + lane)*8 + j ; elem = M[kb*32+(lane>>4)*8+j][nt*16+(lane&15)]
__global__ __launch_bounds__(256)
void k_prep(const float* __restrict__ Wi, const float* __restrict__ Wf,
            const float* __restrict__ Wo, const float* __restrict__ Wu,
            const float* __restrict__ Ui, const float* __restrict__ Uf,
            const float* __restrict__ Uo, const float* __restrict__ Uu,
            bf16_t* __restrict__ SW)
{
    int b = blockIdx.x;
    const float* src;
    switch (b) {
        case 0: src = Wi; break; case 1: src = Wf; break;
        case 2: src = Wo; break; case 3: src = Wu; break;
        case 4: src = Ui; break; case 5: src = Uf; break;
        case 6: src = Uo; break; default: src = Uu; break;
    }
    if (b < 4) {
        bf16_t* hi = SW + (size_t)b * 16384;
        for (int idx = threadIdx.x; idx < 16384; idx += 256) {
            int j = idx & 7, ln = (idx >> 3) & 63, kb = (idx >> 9) & 3, nt = idx >> 11;
            int k = kb * 32 + (ln >> 4) * 8 + j;
            int n = nt * 16 + (ln & 15);
            hi[idx] = (bf16_t)src[k * 128 + n];
        }
    } else {
        bf16_t* hi = SW + 65536 + (size_t)(b - 4) * 32768;
        bf16_t* lo = hi + 16384;
        for (int idx = threadIdx.x; idx < 16384; idx += 256) {
            int j = idx & 7, ln = (idx >> 3) & 63, kb = (idx >> 9) & 3, nt = idx >> 11;
            int k = kb * 32 + (ln >> 4) * 8 + j;
            int n = nt * 16 + (ln & 15);
            float w = src[k * 128 + n];
            bf16_t hh = (bf16_t)w;
            hi[idx] = hh;
            lo[idx] = (bf16_t)(w - (float)hh);
        }
    }
}

// ---------------------------------------------------------------------------
// node32_wave: ONE wave computes 32 internal nodes x 16 cols (col-tile ct),
// full K=128, FULL VALIDITY (32 nodes, 64 children). Children h from CH
// (LDS, 64 rows). Children c: global fp32 (ccLds=0, ccBase = shifted child
// row base) or LDS bf16 BCc (ccLds=1). Output: BH/BC LDS rows outRowOff..
// (outLds=1) or global H/C at outBase (outLds=0).
// Contains ONE uniform __syncthreads() between the MMA loop (last XA/CH
// reads) and the SCw epilogue writes — SCw may alias the XA/CH region.
__device__ __forceinline__ void node32_wave(
    const bf16_t* __restrict__ SW,
    const float* __restrict__ bi, const float* __restrict__ bf_,
    const float* __restrict__ bo, const float* __restrict__ bu,
    const bf16_t (* __restrict__ XA)[136],
    const bf16_t (* __restrict__ CH)[136],
    const float* __restrict__ Cglob, int ccBase,
    const bf16_t (* __restrict__ BCc)[136], int ccLds,
    float (* __restrict__ SCw)[17],
    int ct,
    bf16_t (* __restrict__ BHo)[136], bf16_t (* __restrict__ BCo)[136],
    int outRowOff, int outLds,
    bf16_t* __restrict__ Hg, float* __restrict__ Cg, int outBase,
    int lane)
{
    const int quad = lane >> 4, lc = lane & 15;
    f32x4 z4 = (f32x4){0.f, 0.f, 0.f, 0.f};
    f32x4 aI0 = z4, aI1 = z4, aXf0 = z4, aXf1 = z4;
    f32x4 aO0 = z4, aO1 = z4, aU0 = z4, aU1 = z4;
    f32x4 aF0 = z4, aF1 = z4, aF2 = z4, aF3 = z4;

#pragma unroll
    for (int kb = 0; kb < 4; kb++) {
        const int k0 = kb * 32 + quad * 8;
        bf16x8 xa0 = *(const bf16x8*)&XA[lc][k0];
        bf16x8 xa1 = *(const bf16x8*)&XA[16 + lc][k0];
        bf16x8 h00 = *(const bf16x8*)&CH[2 * lc][k0];
        bf16x8 h01 = *(const bf16x8*)&CH[2 * lc + 1][k0];
        bf16x8 h10 = *(const bf16x8*)&CH[2 * lc + 32][k0];
        bf16x8 h11 = *(const bf16x8*)&CH[2 * lc + 33][k0];
        bf16x8 at0, at1;
#pragma unroll
        for (int j = 0; j < 8; j++) {
            at0[j] = (bf16_t)((float)h00[j] + (float)h01[j]);
            at1[j] = (bf16_t)((float)h10[j] + (float)h11[j]);
        }
        bf16x8 ac0 = *(const bf16x8*)&CH[lc][k0];
        bf16x8 ac1 = *(const bf16x8*)&CH[16 + lc][k0];
        bf16x8 ac2 = *(const bf16x8*)&CH[32 + lc][k0];
        bf16x8 ac3 = *(const bf16x8*)&CH[48 + lc][k0];

        const size_t boff = ((size_t)(ct * 4 + kb) * 64 + lane) * 8;
        bf16x8 bWi = *(const bf16x8*)(SW + boff);
        bf16x8 bWf = *(const bf16x8*)(SW + 16384 + boff);
        bf16x8 bWo = *(const bf16x8*)(SW + 32768 + boff);
        bf16x8 bWu = *(const bf16x8*)(SW + 49152 + boff);
        const bf16_t* Ub = SW + 65536;
        bf16x8 bIh = *(const bf16x8*)(Ub + boff);
        bf16x8 bIl = *(const bf16x8*)(Ub + 16384 + boff);
        bf16x8 bFh = *(const bf16x8*)(Ub + 32768 + boff);
        bf16x8 bFl = *(const bf16x8*)(Ub + 49152 + boff);
        bf16x8 bOh = *(const bf16x8*)(Ub + 65536 + boff);
        bf16x8 bOl = *(const bf16x8*)(Ub + 81920 + boff);
        bf16x8 bUh = *(const bf16x8*)(Ub + 98304 + boff);
        bf16x8 bUl = *(const bf16x8*)(Ub + 114688 + boff);

        aI0  = MFMA16(xa0, bWi, aI0);  aI1  = MFMA16(xa1, bWi, aI1);
        aXf0 = MFMA16(xa0, bWf, aXf0); aXf1 = MFMA16(xa1, bWf, aXf1);
        aO0  = MFMA16(xa0, bWo, aO0);  aO1  = MFMA16(xa1, bWo, aO1);
        aU0  = MFMA16(xa0, bWu, aU0);  aU1  = MFMA16(xa1, bWu, aU1);
        aI0 = MFMA16(at0, bIh, aI0); aI0 = MFMA16(at0, bIl, aI0);
        aI1 = MFMA16(at1, bIh, aI1); aI1 = MFMA16(at1, bIl, aI1);
        aO0 = MFMA16(at0, bOh, aO0); aO0 = MFMA16(at0, bOl, aO0);
        aO1 = MFMA16(at1, bOh, aO1); aO1 = MFMA16(at1, bOl, aO1);
        aU0 = MFMA16(at0, bUh, aU0); aU0 = MFMA16(at0, bUl, aU0);
        aU1 = MFMA16(at1, bUh, aU1); aU1 = MFMA16(at1, bUl, aU1);
        aF0 = MFMA16(ac0, bFh, aF0); aF0 = MFMA16(ac0, bFl, aF0);
        aF1 = MFMA16(ac1, bFh, aF1); aF1 = MFMA16(ac1, bFl, aF1);
        aF2 = MFMA16(ac2, bFh, aF2); aF2 = MFMA16(ac2, bFl, aF2);
        aF3 = MFMA16(ac3, bFh, aF3); aF3 = MFMA16(ac3, bFl, aF3);
    }

    const int colg = ct * 16 + lc;
    // children c prefetch (before the barrier: global latency overlaps; BC
    // LDS reads are from a non-aliased region, visible via caller barrier)
    float c0v[4][2], c1v[4][2];
#pragma unroll
    for (int m2 = 0; m2 < 4; m2++)
#pragma unroll
        for (int pi = 0; pi < 2; pi++) {
            int pl = m2 * 8 + quad * 2 + pi;
            if (ccLds) {
                c0v[m2][pi] = (float)BCc[2 * pl][colg];
                c1v[m2][pi] = (float)BCc[2 * pl + 1][colg];
            } else {
                size_t cr = (size_t)(ccBase + 2 * pl) * 128 + colg;
                c0v[m2][pi] = Cglob[cr];
                c1v[m2][pi] = Cglob[cr + 128];
            }
        }

    __syncthreads();   // all waves' XA/CH reads done -> SCw (alias) writable

    // xf (+bias) exchange via wave-private LDS (in-wave RAW; verified)
    float bfv = bf_[colg];
#pragma unroll
    for (int r = 0; r < 4; r++) {
        SCw[quad * 4 + r][lc]      = aXf0[r] + bfv;
        SCw[16 + quad * 4 + r][lc] = aXf1[r] + bfv;
    }
#define NS_FPATH(M2, AF)                                            \
    _Pragma("unroll")                                               \
    for (int pi = 0; pi < 2; pi++) {                                \
        int pl = M2 * 8 + quad * 2 + pi;                            \
        float xf = SCw[pl][lc];                                     \
        float f0 = sigm(xf + AF[2 * pi]);                           \
        float f1 = sigm(xf + AF[2 * pi + 1]);                       \
        SCw[pl][lc] = f0 * c0v[M2][pi] + f1 * c1v[M2][pi];          \
    }
    NS_FPATH(0, aF0) NS_FPATH(1, aF1) NS_FPATH(2, aF2) NS_FPATH(3, aF3)
#undef NS_FPATH
    float bii = bi[colg], boi = bo[colg], bui = bu[colg];
#define NS_IOU(MT, AI, AO, AU)                                      \
    _Pragma("unroll")                                               \
    for (int r = 0; r < 4; r++) {                                   \
        int pl = MT * 16 + quad * 4 + r;                            \
        float iv = sigm(AI[r] + bii);                               \
        float ov = sigm(AO[r] + boi);                               \
        float uv = tanh_(AU[r] + bui);                              \
        float cv = iv * uv + SCw[pl][lc];                           \
        float hv = ov * tanh_(cv);                                  \
        if (outLds) {                                               \
            BHo[outRowOff + pl][colg] = (bf16_t)hv;                 \
            BCo[outRowOff + pl][colg] = (bf16_t)cv;                 \
        } else {                                                    \
            Hg[(size_t)(outBase + pl) * 128 + colg] = (bf16_t)hv;   \
            Cg[(size_t)(outBase + pl) * 128 + colg] = cv;           \
        }                                                           \
    }
    NS_IOU(0, aI0, aO0, aU0)
    NS_IOU(1, aI1, aO1, aU1)
#undef NS_IOU
}

// ---------------------------------------------------------------------------
// leaf64_wave: ONE wave computes 64 leaf rows x 16 cols (ct), 3 gates.
// 4 kb x {3 loads, 12 MFMAs}; accs 12 f32x4. -> BH/BC rows 0..63. No SC use.
__device__ __forceinline__ void leaf64_wave(
    const bf16_t* __restrict__ SW,
    const float* __restrict__ bi, const float* __restrict__ bo,
    const float* __restrict__ bu,
    const bf16_t (* __restrict__ XA)[136],
    bf16_t (* __restrict__ BH)[136], bf16_t (* __restrict__ BC)[136],
    int ct, int lane)
{
    const int quad = lane >> 4, lc = lane & 15;
    f32x4 aI[4], aO[4], aU[4];
#pragma unroll
    for (int mt = 0; mt < 4; mt++) {
        aI[mt] = (f32x4){0.f, 0.f, 0.f, 0.f};
        aO[mt] = (f32x4){0.f, 0.f, 0.f, 0.f};
        aU[mt] = (f32x4){0.f, 0.f, 0.f, 0.f};
    }
#pragma unroll
    for (int kb = 0; kb < 4; kb++) {
        const int k0 = kb * 32 + quad * 8;
        bf16x8 a0 = *(const bf16x8*)&XA[lc][k0];
        bf16x8 a1 = *(const bf16x8*)&XA[16 + lc][k0];
        bf16x8 a2 = *(const bf16x8*)&XA[32 + lc][k0];
        bf16x8 a3 = *(const bf16x8*)&XA[48 + lc][k0];
        const size_t boff = ((size_t)(ct * 4 + kb) * 64 + lane) * 8;
        bf16x8 bWi = *(const bf16x8*)(SW + boff);
        bf16x8 bWo = *(const bf16x8*)(SW + 32768 + boff);
        bf16x8 bWu = *(const bf16x8*)(SW + 49152 + boff);
        aI[0] = MFMA16(a0, bWi, aI[0]); aI[1] = MFMA16(a1, bWi, aI[1]);
        aI[2] = MFMA16(a2, bWi, aI[2]); aI[3] = MFMA16(a3, bWi, aI[3]);
        aO[0] = MFMA16(a0, bWo, aO[0]); aO[1] = MFMA16(a1, bWo, aO[1]);
        aO[2] = MFMA16(a2, bWo, aO[2]); aO[3] = MFMA16(a3, bWo, aO[3]);
        aU[0] = MFMA16(a0, bWu, aU[0]); aU[1] = MFMA16(a1, bWu, aU[1]);
        aU[2] = MFMA16(a2, bWu, aU[2]); aU[3] = MFMA16(a3, bWu, aU[3]);
    }
    const int col = ct * 16 + lc;
    float bii = bi[col], boi = bo[col], bui = bu[col];
#pragma unroll
    for (int mt = 0; mt < 4; mt++)
#pragma unroll
        for (int r = 0; r < 4; r++) {
            float iv = sigm(aI[mt][r] + bii);
            float ov = sigm(aO[mt][r] + boi);
            float uv = tanh_(aU[mt][r] + bui);
            float cv = iv * uv;
            int pl = mt * 16 + quad * 4 + r;
            BH[pl][col] = (bf16_t)(ov * tanh_(cv));
            BC[pl][col] = (bf16_t)cv;
        }
}

// ---------------------------------------------------------------------------
// k_pairleaf2: 512 thr, 8 waves (wave = col-tile). Block = 32 L(depth-1)
// parents; phase 1 = 64 leaf children (leaf64_wave), phase 2 = parents
// (node32_wave). LDS: XA[64][136] @0 | BH @17408 | BC @34816 |
// SC[8][32][17]f32 @0 (ALIAS of XA — protected by node32_wave's internal
// barrier). Total 52224 -> 3 blocks/CU.
__global__ __launch_bounds__(512)
void k_pairleaf2(const float* __restrict__ x, const bf16_t* __restrict__ SW,
                 const float* __restrict__ bi, const float* __restrict__ bf_,
                 const float* __restrict__ bo, const float* __restrict__ bu,
                 bf16_t* __restrict__ H, float* __restrict__ C, int Pa)
{
    __shared__ __align__(16) char smem[52224];
    bf16_t (*XA)[136] = (bf16_t(*)[136])(smem);
    bf16_t (*BH)[136] = (bf16_t(*)[136])(smem + 17408);
    bf16_t (*BC)[136] = (bf16_t(*)[136])(smem + 34816);
    float  (*SC)[32][17] = (float(*)[32][17])(smem);   // alias XA

    const int tid = threadIdx.x;
    const int wave = tid >> 6, lane = tid & 63;
    const int sA0 = Pa + 32 * blockIdx.x;

    {   // stage 64 leaf x rows (shifted leaf base 2*sA0; x row = shifted-1)
        int r = tid >> 3, cb = (tid & 7) * 16;
        cvt16(x + (size_t)(2 * sA0 - 1 + r) * 128 + cb, &XA[r][cb]);
    }
    __syncthreads();
    leaf64_wave(SW, bi, bo, bu, (const bf16_t(*)[136])XA, BH, BC, wave, lane);
    __syncthreads();   // leaf XA reads done; BH/BC visible
    {   // stage 32 parent x rows
        int r = tid >> 3, cb = (tid & 7) * 16;
        if (r < 32) cvt16(x + (size_t)(sA0 - 1 + r) * 128 + cb, &XA[r][cb]);
    }
    __syncthreads();
    node32_wave(SW, bi, bf_, bo, bu,
                (const bf16_t(*)[136])XA, (const bf16_t(*)[136])BH,
                nullptr, 0, (const bf16_t(*)[136])BC, 1,
                SC[wave], wave,
                nullptr, nullptr, 0, 0,
                H, C, sA0, lane);
}

// ---------------------------------------------------------------------------
// k_pairint2: 512 thr, 8 waves. Internal 2-level pair, FULL VALIDITY ONLY
// (Pa multiple of 32 and >= 32; used at A=14). Two mid q-phases (children
// h from global H bf16, children c from global C fp32) fill BH/BC; top phase
// consumes them. LDS: XA[32][136] @0 | HC[64][136] @8704 | BH @26112 |
// BC @43520 | SC[8][32][17] @0 (ALIAS of XA+HC prefix, barrier-protected).
// Total 60928 -> 2 blocks/CU (16 waves/CU at 512 thr).
__global__ __launch_bounds__(512)
void k_pairint2(const float* __restrict__ x, const bf16_t* __restrict__ SW,
                const float* __restrict__ bi, const float* __restrict__ bf_,
                const float* __restrict__ bo, const float* __restrict__ bu,
                bf16_t* __restrict__ H, float* __restrict__ C, int Pa)
{
    __shared__ __align__(16) char smem[60928];
    bf16_t (*XA)[136] = (bf16_t(*)[136])(smem);
    bf16_t (*HC)[136] = (bf16_t(*)[136])(smem + 8704);
    bf16_t (*BH)[136] = (bf16_t(*)[136])(smem + 26112);
    bf16_t (*BC)[136] = (bf16_t(*)[136])(smem + 43520);
    float  (*SC)[32][17] = (float(*)[32][17])(smem);   // alias XA+HC prefix

    const int tid = threadIdx.x;
    const int wave = tid >> 6, lane = tid & 63;
    const int sA0 = Pa + 32 * blockIdx.x;

    for (int q = 0; q < 2; q++) {
        {   // stage mid x rows (shifted 2*sA0 + 32q + r; x row = shifted-1)
            int r = tid >> 3, cb = (tid & 7) * 16;
            if (r < 32) cvt16(x + (size_t)(2 * sA0 + 32 * q - 1 + r) * 128 + cb, &XA[r][cb]);
        }
        {   // stage 64 children h rows (level A+2): shifted 4*sA0 + 64q + r
            int r = tid >> 3, cb = (tid & 7) * 16;
            const uint4* src = (const uint4*)(H + (size_t)(4 * sA0 + 64 * q + r) * 128 + cb);
            *(uint4*)&HC[r][cb]     = src[0];
            *(uint4*)&HC[r][cb + 8] = src[1];
        }
        __syncthreads();
        node32_wave(SW, bi, bf_, bo, bu,
                    (const bf16_t(*)[136])XA, (const bf16_t(*)[136])HC,
                    C, 4 * sA0 + 64 * q, nullptr, 0,
                    SC[wave], wave,
                    BH, BC, 32 * q, 1,
                    nullptr, nullptr, 0, lane);
        __syncthreads();   // epilogue SC writes (over XA/HC) done -> restage ok
    }

    {   // stage top x rows (shifted sA0 + r)
        int r = tid >> 3, cb = (tid & 7) * 16;
        if (r < 32) cvt16(x + (size_t)(sA0 - 1 + r) * 128 + cb, &XA[r][cb]);
    }
    __syncthreads();
    node32_wave(SW, bi, bf_, bo, bu,
                (const bf16_t(*)[136])XA, (const bf16_t(*)[136])BH,
                nullptr, 0, (const bf16_t(*)[136])BC, 1,
                SC[wave], wave,
                nullptr, nullptr, 0, 0,
                H, C, sA0, lane);
}

// ---------------------------------------------------------------------------
// k_lvl: VERIFIED R5 version, unchanged. Levels 13..0.
__global__ __launch_bounds__(256, 2)
void k_lvl(const float* __restrict__ x, const bf16_t* __restrict__ SW,
           const float* __restrict__ bi, const float* __restrict__ bf_,
           const float* __restrict__ bo, const float* __restrict__ bu,
           bf16_t* H, float* C, int np)
{
    __shared__ __align__(16) char smem[75264];
    f32x4  (*PR)[4][64] = (f32x4(*)[4][64])smem;
    bf16_t (*XA)[136]   = (bf16_t(*)[136])(smem + 49152);
    bf16_t (*CH)[136]   = (bf16_t(*)[136])(smem + 57856);
    float  (*SC)[17]    = (float(*)[17])smem;

    const int tid = threadIdx.x;
    const int wave = tid >> 6, lane = tid & 63;
    const int quad = lane >> 4, lc = lane & 15;

    const int task = blockIdx.x;
    const int ct = task & 7, mt = task >> 3;
    int valid = np - 32 * mt; if (valid > 32) valid = 32;
    if (valid <= 0) return;
    const int prow = np + 32 * mt;
    const int crow = 2 * np + 64 * mt;

    {   // stage XA
        int r = tid >> 3, cb = (tid & 7) * 16;
        if (r < valid) cvt16(x + (size_t)(prow - 1 + r) * 128 + cb, &XA[r][cb]);
        else           zero16(&XA[r][cb]);
    }
    {   // stage CH
        int r = tid >> 2, cb = (tid & 3) * 32;
        if (r < 2 * valid) {
            const uint4* src = (const uint4*)(H + (size_t)(crow + r) * 128 + cb);
            *(uint4*)&CH[r][cb]      = src[0];
            *(uint4*)&CH[r][cb + 8]  = src[1];
            *(uint4*)&CH[r][cb + 16] = src[2];
            *(uint4*)&CH[r][cb + 24] = src[3];
        } else {
            uint4 z = {0u, 0u, 0u, 0u};
            *(uint4*)&CH[r][cb]      = z;
            *(uint4*)&CH[r][cb + 8]  = z;
            *(uint4*)&CH[r][cb + 16] = z;
            *(uint4*)&CH[r][cb + 24] = z;
        }
    }
    __syncthreads();

    f32x4 z4 = (f32x4){0.f, 0.f, 0.f, 0.f};
    f32x4 aI0 = z4, aI1 = z4, aXf0 = z4, aXf1 = z4;
    f32x4 aO0 = z4, aO1 = z4, aU0 = z4, aU1 = z4;
    f32x4 aF0 = z4, aF1 = z4, aF2 = z4, aF3 = z4;
    {
        const int k0 = wave * 32 + quad * 8;
        bf16x8 xa0 = *(const bf16x8*)&XA[lc][k0];
        bf16x8 xa1 = *(const bf16x8*)&XA[16 + lc][k0];
        bf16x8 h00 = *(const bf16x8*)&CH[2 * lc][k0];
        bf16x8 h01 = *(const bf16x8*)&CH[2 * lc + 1][k0];
        bf16x8 h10 = *(const bf16x8*)&CH[2 * lc + 32][k0];
        bf16x8 h11 = *(const bf16x8*)&CH[2 * lc + 33][k0];
        bf16x8 at0, at1;
#pragma unroll
        for (int j = 0; j < 8; j++) {
            at0[j] = (bf16_t)((float)h00[j] + (float)h01[j]);
            at1[j] = (bf16_t)((float)h10[j] + (float)h11[j]);
        }
        bf16x8 ac0 = *(const bf16x8*)&CH[lc][k0];
        bf16x8 ac1 = *(const bf16x8*)&CH[16 + lc][k0];
        bf16x8 ac2 = *(const bf16x8*)&CH[32 + lc][k0];
        bf16x8 ac3 = *(const bf16x8*)&CH[48 + lc][k0];

        const size_t boff = ((size_t)(ct * 4 + wave) * 64 + lane) * 8;
        bf16x8 bWi = *(const bf16x8*)(SW + boff);
        bf16x8 bWf = *(const bf16x8*)(SW + 16384 + boff);
        bf16x8 bWo = *(const bf16x8*)(SW + 32768 + boff);
        bf16x8 bWu = *(const bf16x8*)(SW + 49152 + boff);
        const bf16_t* Ub = SW + 65536;
        bf16x8 bIh = *(const bf16x8*)(Ub + boff);
        bf16x8 bIl = *(const bf16x8*)(Ub + 16384 + boff);
        bf16x8 bFh = *(const bf16x8*)(Ub + 32768 + boff);
        bf16x8 bFl = *(const bf16x8*)(Ub + 49152 + boff);
        bf16x8 bOh = *(const bf16x8*)(Ub + 65536 + boff);
        bf16x8 bOl = *(const bf16x8*)(Ub + 81920 + boff);
        bf16x8 bUh = *(const bf16x8*)(Ub + 98304 + boff);
        bf16x8 bUl = *(const bf16x8*)(Ub + 114688 + boff);

        aI0  = MFMA16(xa0, bWi, aI0);  aI1  = MFMA16(xa1, bWi, aI1);
        aXf0 = MFMA16(xa0, bWf, aXf0); aXf1 = MFMA16(xa1, bWf, aXf1);
        aO0  = MFMA16(xa0, bWo, aO0);  aO1  = MFMA16(xa1, bWo, aO1);
        aU0  = MFMA16(xa0, bWu, aU0);  aU1  = MFMA16(xa1, bWu, aU1);
        aI0 = MFMA16(at0, bIh, aI0); aI0 = MFMA16(at0, bIl, aI0);
        aI1 = MFMA16(at1, bIh, aI1); aI1 = MFMA16(at1, bIl, aI1);
        aO0 = MFMA16(at0, bOh, aO0); aO0 = MFMA16(at0, bOl, aO0);
        aO1 = MFMA16(at1, bOh, aO1); aO1 = MFMA16(at1, bOl, aO1);
        aU0 = MFMA16(at0, bUh, aU0); aU0 = MFMA16(at0, bUl, aU0);
        aU1 = MFMA16(at1, bUh, aU1); aU1 = MFMA16(at1, bUl, aU1);
        aF0 = MFMA16(ac0, bFh, aF0); aF0 = MFMA16(ac0, bFl, aF0);
        aF1 = MFMA16(ac1, bFh, aF1); aF1 = MFMA16(ac1, bFl, aF1);
        aF2 = MFMA16(ac2, bFh, aF2); aF2 = MFMA16(ac2, bFl, aF2);
        aF3 = MFMA16(ac3, bFh, aF3); aF3 = MFMA16(ac3, bFl, aF3);
    }
    if (wave != 0) {
        PR[0][wave][lane]  = aI0;  PR[1][wave][lane]  = aI1;
        PR[2][wave][lane]  = aXf0; PR[3][wave][lane]  = aXf1;
        PR[4][wave][lane]  = aO0;  PR[5][wave][lane]  = aO1;
        PR[6][wave][lane]  = aU0;  PR[7][wave][lane]  = aU1;
        PR[8][wave][lane]  = aF0;  PR[9][wave][lane]  = aF1;
        PR[10][wave][lane] = aF2;  PR[11][wave][lane] = aF3;
    }
    __syncthreads();
    if (wave == 0) {
        aI0  += PR[0][1][lane]  + PR[0][2][lane]  + PR[0][3][lane];
        aI1  += PR[1][1][lane]  + PR[1][2][lane]  + PR[1][3][lane];
        aXf0 += PR[2][1][lane]  + PR[2][2][lane]  + PR[2][3][lane];
        aXf1 += PR[3][1][lane]  + PR[3][2][lane]  + PR[3][3][lane];
        aO0  += PR[4][1][lane]  + PR[4][2][lane]  + PR[4][3][lane];
        aO1  += PR[5][1][lane]  + PR[5][2][lane]  + PR[5][3][lane];
        aU0  += PR[6][1][lane]  + PR[6][2][lane]  + PR[6][3][lane];
        aU1  += PR[7][1][lane]  + PR[7][2][lane]  + PR[7][3][lane];
        aF0  += PR[8][1][lane]  + PR[8][2][lane]  + PR[8][3][lane];
        aF1  += PR[9][1][lane]  + PR[9][2][lane]  + PR[9][3][lane];
        aF2  += PR[10][1][lane] + PR[10][2][lane] + PR[10][3][lane];
        aF3  += PR[11][1][lane] + PR[11][2][lane] + PR[11][3][lane];

        const int colg = ct * 16 + lc;
        float c0v[4][2], c1v[4][2];
#pragma unroll
        for (int m2 = 0; m2 < 4; m2++)
#pragma unroll
            for (int pi = 0; pi < 2; pi++) {
                int pl = m2 * 8 + quad * 2 + pi;
                size_t cr = (size_t)(crow + 2 * pl) * 128 + colg;
                c0v[m2][pi] = C[cr];
                c1v[m2][pi] = C[cr + 128];
            }
        float bfv = bf_[colg];
#pragma unroll
        for (int r = 0; r < 4; r++) {
            SC[quad * 4 + r][lc]      = aXf0[r] + bfv;
            SC[16 + quad * 4 + r][lc] = aXf1[r] + bfv;
        }
#define NS_FPATH(M2, AF)                                            \
        _Pragma("unroll")                                           \
        for (int pi = 0; pi < 2; pi++) {                            \
            int pl = M2 * 8 + quad * 2 + pi;                        \
            float xf = SC[pl][lc];                                  \
            float f0 = sigm(xf + AF[2 * pi]);                       \
            float f1 = sigm(xf + AF[2 * pi + 1]);                   \
            SC[pl][lc] = f0 * c0v[M2][pi] + f1 * c1v[M2][pi];       \
        }
        NS_FPATH(0, aF0) NS_FPATH(1, aF1) NS_FPATH(2, aF2) NS_FPATH(3, aF3)
#undef NS_FPATH
        float bii = bi[colg], boi = bo[colg], bui = bu[colg];
#define NS_IOU(MT, AI, AO, AU)                                      \
        _Pragma("unroll")                                           \
        for (int r = 0; r < 4; r++) {                               \
            int pl = MT * 16 + quad * 4 + r;                        \
            float iv = sigm(AI[r] + bii);                           \
            float ov = sigm(AO[r] + boi);                           \
            float uv = tanh_(AU[r] + bui);                          \
            float cv = iv * uv + SC[pl][lc];                        \
            if (pl < valid) {                                       \
                H[(size_t)(prow + pl) * 128 + colg] = (bf16_t)(ov * tanh_(cv)); \
                C[(size_t)(prow + pl) * 128 + colg] = cv;           \
            }                                                       \
        }
        NS_IOU(0, aI0, aO0, aU0)
        NS_IOU(1, aI1, aO1, aU1)
#undef NS_IOU
    }
}

__global__ __launch_bounds__(256)
void k_out(const bf16_t* __restrict__ H, const float* __restrict__ C,
           float* __restrict__ out)
{
    int t = threadIdx.x;
    if (t < 128)      out[t] = (float)H[128 + t];   // shifted row 1 = root
    else if (t < 256) out[t] = C[t];                // C[128 + (t-128)]
}

// ---------------------------------------------------------------------------
extern "C" void kernel_launch(void* const* d_in, const int* in_sizes, int n_in,
                              void* d_out, int out_size, void* d_ws, size_t ws_size,
                              hipStream_t stream)
{
    const float* x   = (const float*)d_in[0];
    const float* Wi  = (const float*)d_in[1];
    const float* bi  = (const float*)d_in[2];
    const float* Ui  = (const float*)d_in[3];
    const float* Wf  = (const float*)d_in[4];
    const float* bf_ = (const float*)d_in[5];
    const float* Uf  = (const float*)d_in[6];
    const float* Wo  = (const float*)d_in[7];
    const float* bo  = (const float*)d_in[8];
    const float* Uo  = (const float*)d_in[9];
    const float* Wu  = (const float*)d_in[10];
    const float* bu  = (const float*)d_in[11];
    const float* Uu  = (const float*)d_in[12];

    int Ntot  = in_sizes[0] / 128;
    int depth = 31 - __builtin_clz((unsigned)(Ntot + 1)) - 1;

    // workspace: SW 384 KB | H bf16 (Ntot+1)*128 | C fp32 (Ntot+1)*128
    char* w = (char*)d_ws;
    bf16_t* SW = (bf16_t*)w;  w += 393216;
    bf16_t* H  = (bf16_t*)w;  w += (size_t)(Ntot + 1) * 128 * sizeof(bf16_t);
    float*  C  = (float*)w;

    k_prep<<<8, 256, 0, stream>>>(Wi, Wf, Wo, Wu, Ui, Uf, Uo, Uu, SW);

    {   // levels depth + depth-1 (leaves fused), 3 blocks/CU
        int Pa = 1 << (depth - 1);
        k_pairleaf2<<<Pa / 32, 512, 0, stream>>>(x, SW, bi, bf_, bo, bu, H, C, Pa);
    }
    int lowest = depth - 1;
    if (depth - 3 >= 5) {   // A = depth-3 via wave-per-col-tile internal pair
        int Pa = 1 << (depth - 3);
        k_pairint2<<<Pa / 32, 512, 0, stream>>>(x, SW, bi, bf_, bo, bu, H, C, Pa);
        lowest = depth - 3;
    }
    // remaining levels: one latency-optimized launch per level (verified)
    for (int l = lowest - 1; l >= 0; l--) {
        int np = 1 << l;
        int nmt = (np + 31) / 32;
        k_lvl<<<nmt * 8, 256, 0, stream>>>(x, SW, bi, bf_, bo, bu, H, C, np);
    }
    k_out<<<1, 256, 0, stream>>>(H, C, (float*)d_out);
}